// Round 3
// baseline (723.556 us; speedup 1.0000x reference)
//
#include <hip/hip_runtime.h>

#define N_ENT 100000
#define DIM 512
#define RANK 256
#define HROWS 256
#define MAXOBS 32
#define BROWS 64    // q-rows per block
#define BCOLS 256   // entities per block (16 waves x 16)

typedef __attribute__((ext_vector_type(8))) short short8_t;
typedef __attribute__((ext_vector_type(4))) float f32x4;

__device__ __forceinline__ unsigned short f2bf(float f) {
  unsigned int x = __float_as_uint(f);
  x = x + 0x7fffu + ((x >> 16) & 1u);
  return (unsigned short)(x >> 16);
}

// ---- mask format handling (bool storage dtype is harness-dependent) ----
__device__ __forceinline__ int mask_mode(const int* flags) {
  int nz0 = flags[0], nz1 = flags[1], nz2 = flags[2], nz3 = flags[3];
  if (nz1 || (nz0 && (nz2 | nz3))) return 0;  // uint8
  if (nz0) return 1;                          // int32
  if (nz2 | nz3) return 2;                    // float32
  return 0;
}

__device__ __forceinline__ int mask_at(const void* mask, int idx, int mode) {
  if (mode == 0) return ((const unsigned char*)mask)[idx] != 0;
  if (mode == 1) return ((const int*)mask)[idx] != 0;
  return ((const float*)mask)[idx] != 0.0f;
}

__global__ void detect_mask_kernel(const unsigned char* __restrict__ mb, int* flags) {
  int t = threadIdx.x;
  int nz[4] = {0, 0, 0, 0};
  for (int j = 0; j < 32; ++j) {
    int idx = t * 32 + j;
    if (mb[idx]) nz[idx & 3] = 1;
  }
  for (int r = 0; r < 4; ++r)
    if (nz[r]) atomicOr(&flags[r], 1);
}

// ---- head extraction ----
__global__ void find_heads_kernel(const float* __restrict__ vec, int* counter, int* tmp) {
  int i = blockIdx.x * blockDim.x + threadIdx.x;
  if (i < N_ENT && vec[i] != 0.0f) {
    int p = atomicAdd(counter, 1);
    if (p < HROWS) tmp[p] = i;
  }
}

__global__ void sort_heads_kernel(const int* __restrict__ counter, const int* __restrict__ tmp,
                                  int* __restrict__ heads) {
  __shared__ int v[HROWS];
  int t = threadIdx.x;
  int cnt = *counter;
  if (cnt > HROWS) cnt = HROWS;
  v[t] = (t < cnt) ? tmp[t] : 0x7fffffff;
  __syncthreads();
  for (int k = 2; k <= HROWS; k <<= 1) {
    for (int j = k >> 1; j > 0; j >>= 1) {
      int ixj = t ^ j;
      if (ixj > t) {
        int a = v[t], b = v[ixj];
        bool up = ((t & k) == 0);
        if ((a > b) == up) { v[t] = b; v[ixj] = a; }
      }
      __syncthreads();
    }
  }
  heads[t] = (v[t] == 0x7fffffff) ? 0 : v[t];
}

// ---- query build: writes q PRE-SWIZZLED (16B-slot XOR by row&7) ----
__global__ void build_q_kernel(const float* __restrict__ ent, const float* __restrict__ rel,
                               const int* __restrict__ heads, const int* __restrict__ rel_id,
                               unsigned short* __restrict__ qsw) {
  int b = blockIdx.x, k = threadIdx.x;  // k in 0..255
  int h = heads[b];
  const float* r = rel + (size_t)(*rel_id) * (2 * RANK);
  float re_h = ent[(size_t)h * DIM + k];
  float im_h = ent[(size_t)h * DIM + RANK + k];
  float re_r = r[k], im_r = r[RANK + k];
  const int sw = b & 7;
  const int i1 = ((((k >> 3) ^ sw) << 3) | (k & 7));
  const int i2 = (((((k >> 3) + 32) ^ sw) << 3) | (k & 7));
  qsw[(size_t)b * DIM + i1] = f2bf(re_h * re_r - im_h * im_r);
  qsw[(size_t)b * DIM + i2] = f2bf(re_h * im_r + im_h * re_r);
}

// ---- GEMM: out = exp(q @ ent^T), rowsum via atomics. Barrier-free stream. ----
// grid 1568 blocks: bid -> (colb 0..391, rowb 0..3); 4 row-sharers of a col
// slab land on the same XCD, adjacent in dispatch (L2 absorbs 4x re-read).
__global__ __launch_bounds__(1024) void gemm_scores_kernel(
    const float* __restrict__ ent, const unsigned short* __restrict__ qsw,
    float* __restrict__ out, float* __restrict__ rowsum) {
  __shared__ __align__(16) unsigned short As[BROWS * DIM];  // 64KB, swizzled rows

  const int t = threadIdx.x;
  const int lane = t & 63;
  const int w = t >> 6;        // wave 0..15
  const int l15 = lane & 15;
  const int lk = lane >> 4;    // 0..3

  const int bid = blockIdx.x;
  const int xcd = bid & 7;
  const int sgrp = bid >> 3;
  const int rowb = sgrp & 3;
  const int colb = (sgrp >> 2) * 8 + xcd;
  if (colb * BCOLS >= N_ENT) return;  // pad block: whole block exits pre-barrier

  const int e0 = colb * BCOLS + w * 16;  // wave's 16 entity cols
  const int er = e0 + l15;
  const bool valid = er < N_ENT;
  const int erc = valid ? er : (N_ENT - 1);
  const float* bp = ent + (size_t)erc * DIM + lk * 8;

  // B kfrag 0 prefetch (in flight during A staging)
  float4 cb0 = *reinterpret_cast<const float4*>(bp);
  float4 cb1 = *reinterpret_cast<const float4*>(bp + 4);

  // stage A once: 64 rows x 512 k bf16, linear copy of pre-swizzled image
  {
    const unsigned short* src = qsw + (size_t)(rowb * BROWS) * DIM;
#pragma unroll
    for (int i = 0; i < 4; ++i) {
      const int row = i * 16 + w;
      __builtin_amdgcn_global_load_lds(
          (const __attribute__((address_space(1))) void*)(src + row * DIM + lane * 8),
          (__attribute__((address_space(3))) void*)((char*)As + row * 1024),
          16, 0, 0);
    }
  }
  __syncthreads();  // the only barrier

  f32x4 acc[4] = {};

  for (int kf = 0; kf < 16; ++kf) {
    float4 n0, n1;
    if (kf < 15) {  // prefetch next kfrag
      n0 = *reinterpret_cast<const float4*>(bp + (kf + 1) * 32);
      n1 = *reinterpret_cast<const float4*>(bp + (kf + 1) * 32 + 4);
    }
    unsigned int r0, r1, r2, r3;
    asm("v_cvt_pk_bf16_f32 %0, %1, %2" : "=v"(r0) : "v"(cb0.x), "v"(cb0.y));
    asm("v_cvt_pk_bf16_f32 %0, %1, %2" : "=v"(r1) : "v"(cb0.z), "v"(cb0.w));
    asm("v_cvt_pk_bf16_f32 %0, %1, %2" : "=v"(r2) : "v"(cb1.x), "v"(cb1.y));
    asm("v_cvt_pk_bf16_f32 %0, %1, %2" : "=v"(r3) : "v"(cb1.z), "v"(cb1.w));
    union { unsigned int u[4]; short8_t s8; } bf;
    bf.u[0] = r0; bf.u[1] = r1; bf.u[2] = r2; bf.u[3] = r3;
#pragma unroll
    for (int rf = 0; rf < 4; ++rf) {
      const int rl = rf * 16 + l15;
      const short8_t a = *reinterpret_cast<const short8_t*>(
          (const char*)As + rl * 1024 + ((((kf << 2) | lk) ^ (rl & 7)) << 4));
      acc[rf] = __builtin_amdgcn_mfma_f32_16x16x32_bf16(a, bf.s8, acc[rf], 0, 0, 0);
    }
    cb0 = n0; cb1 = n1;
  }

  // epilogue: C/D map col=lane&15, row=(lane>>4)*4+reg; store exp(s)
#pragma unroll
  for (int rf = 0; rf < 4; ++rf) {
#pragma unroll
    for (int j = 0; j < 4; ++j) {
      const int grow = rowb * BROWS + rf * 16 + lk * 4 + j;
      float p = __expf(acc[rf][j]);
      float pv = valid ? p : 0.0f;
      if (valid) out[(size_t)grow * N_ENT + er] = p;
      pv += __shfl_xor(pv, 1);
      pv += __shfl_xor(pv, 2);
      pv += __shfl_xor(pv, 4);
      pv += __shfl_xor(pv, 8);
      if (l15 == 0) atomicAdd(&rowsum[grow], pv);
    }
  }
}

// ---- scaling: factor[i] = scaling_i / rowsum_i (out holds exp(s)) ----
__global__ void scaling_kernel(const float* __restrict__ pun, const float* __restrict__ rowsum,
                               const int* __restrict__ obs_idx, const void* __restrict__ mask,
                               const int* __restrict__ flags, float* __restrict__ factor) {
  int i = threadIdx.x;
  int mode = mask_mode(flags);
  float rs = rowsum[i];
  float sume = 0.0f;
  int cnt = 0;
  for (int j = 0; j < 32; ++j) {
    if (mask_at(mask, i * 32 + j, mode)) {
      int tg = obs_idx[i * 32 + j];
      sume += pun[(size_t)i * N_ENT + tg];
      ++cnt;
    }
  }
  float scaling = 1.0f;
  if (cnt > 0) {
    float denom = fmaxf(sume / rs, 1e-30f);
    scaling = (float)cnt / denom;
  }
  factor[i] = scaling / rs;
}

// ---- finalize: out = clamp(threshold(p_un * factor)) in place ----
__global__ __launch_bounds__(256) void finalize_kernel(float* __restrict__ out,
                                                       const float* __restrict__ factor,
                                                       const int* __restrict__ train) {
  int row = blockIdx.y;
  int i4 = blockIdx.x * blockDim.x + threadIdx.x;
  if (i4 >= N_ENT / 4) return;
  float f = factor[row];
  float hi = (*train) ? (1.0f - 0.001f) : 1.0f;
  float4* p = reinterpret_cast<float4*>(out + (size_t)row * N_ENT) + i4;
  float4 v = *p;
  float vals[4] = {v.x, v.y, v.z, v.w};
#pragma unroll
  for (int j = 0; j < 4; ++j) {
    float s = vals[j] * f;
    s = (s > 1e-4f) ? s : 0.0f;
    vals[j] = fminf(s, hi);
  }
  v.x = vals[0]; v.y = vals[1]; v.z = vals[2]; v.w = vals[3];
  *p = v;
}

// ---- observed positions -> 1.0 (train only) ----
__global__ void scatter_obs_kernel(float* __restrict__ out, const int* __restrict__ obs_idx,
                                   const void* __restrict__ mask, const int* __restrict__ flags,
                                   const int* __restrict__ train) {
  if (!(*train)) return;
  int t = blockIdx.x * blockDim.x + threadIdx.x;
  if (t >= HROWS * MAXOBS) return;
  int mode = mask_mode(flags);
  if (mask_at(mask, t, mode))
    out[(size_t)(t >> 5) * N_ENT + obs_idx[t]] = 1.0f;
}

extern "C" void kernel_launch(void* const* d_in, const int* in_sizes, int n_in,
                              void* d_out, int out_size, void* d_ws, size_t ws_size,
                              hipStream_t stream) {
  const float* ent      = (const float*)d_in[0];
  const float* rel      = (const float*)d_in[1];
  const float* head_vec = (const float*)d_in[2];
  const int* obs_idx    = (const int*)d_in[3];
  const void* obs_mask  = d_in[4];
  const int* rel_id     = (const int*)d_in[5];
  const int* train      = (const int*)d_in[7];
  float* out = (float*)d_out;

  char* ws = (char*)d_ws;
  int*   counter = (int*)(ws + 0);
  int*   flags   = (int*)(ws + 4);
  float* rowsum  = (float*)(ws + 64);
  float* factor  = (float*)(ws + 1088);
  int*   tmp     = (int*)(ws + 2112);
  int*   heads   = (int*)(ws + 3136);
  unsigned short* qsw = (unsigned short*)(ws + 4224);  // 256x512 bf16, swizzled

  hipMemsetAsync(ws, 0, 2112, stream);

  detect_mask_kernel<<<1, 256, 0, stream>>>((const unsigned char*)obs_mask, flags);
  find_heads_kernel<<<(N_ENT + 255) / 256, 256, 0, stream>>>(head_vec, counter, tmp);
  sort_heads_kernel<<<1, 256, 0, stream>>>(counter, tmp, heads);
  build_q_kernel<<<HROWS, 256, 0, stream>>>(ent, rel, heads, rel_id, qsw);
  // 392 col-blocks (incl. 1 pad) x 4 row-blocks, XCD-grouped
  gemm_scores_kernel<<<1568, 1024, 0, stream>>>(ent, qsw, out, rowsum);
  scaling_kernel<<<1, 256, 0, stream>>>(out, rowsum, obs_idx, obs_mask, flags, factor);
  finalize_kernel<<<dim3((N_ENT / 4 + 255) / 256, HROWS), 256, 0, stream>>>(out, factor, train);
  scatter_obs_kernel<<<(HROWS * MAXOBS + 255) / 256, 256, 0, stream>>>(out, obs_idx, obs_mask, flags, train);
}

// Round 4
// 190.211 us; speedup vs baseline: 3.8040x; 3.8040x over previous
//
#include <hip/hip_runtime.h>

#define N_ENT 100000
#define DIM 512
#define RANK 256
#define HROWS 256
#define MAXOBS 32
#define NBLK 1563          // ceil(100000/64)
#define BSTRIDE 40         // B tile row stride in shorts (conflict-free, 16B-aligned)

typedef __attribute__((ext_vector_type(8))) short short8_t;
typedef __attribute__((ext_vector_type(4))) float f32x4;
typedef __attribute__((ext_vector_type(4))) unsigned int u32x4;

__device__ __forceinline__ unsigned short f2bf(float f) {
  unsigned int x = __float_as_uint(f);
  x = x + 0x7fffu + ((x >> 16) & 1u);
  return (unsigned short)(x >> 16);
}

// ---- mask format handling (bool storage dtype is harness-dependent) ----
__device__ __forceinline__ int mask_mode(const int* flags) {
  int nz0 = flags[0], nz1 = flags[1], nz2 = flags[2], nz3 = flags[3];
  if (nz1 || (nz0 && (nz2 | nz3))) return 0;  // uint8
  if (nz0) return 1;                          // int32
  if (nz2 | nz3) return 2;                    // float32
  return 0;
}

__device__ __forceinline__ int mask_at(const void* mask, int idx, int mode) {
  if (mode == 0) return ((const unsigned char*)mask)[idx] != 0;
  if (mode == 1) return ((const int*)mask)[idx] != 0;
  return ((const float*)mask)[idx] != 0.0f;
}

__global__ void detect_mask_kernel(const unsigned char* __restrict__ mb, int* flags) {
  int t = threadIdx.x;
  int nz[4] = {0, 0, 0, 0};
  for (int j = 0; j < 32; ++j) {
    int idx = t * 32 + j;
    if (mb[idx]) nz[idx & 3] = 1;
  }
  for (int r = 0; r < 4; ++r)
    if (nz[r]) atomicOr(&flags[r], 1);
}

// ---- head extraction ----
__global__ void find_heads_kernel(const float* __restrict__ vec, int* counter, int* tmp) {
  int i = blockIdx.x * blockDim.x + threadIdx.x;
  if (i < N_ENT && vec[i] != 0.0f) {
    int p = atomicAdd(counter, 1);
    if (p < HROWS) tmp[p] = i;
  }
}

__global__ void sort_heads_kernel(const int* __restrict__ counter, const int* __restrict__ tmp,
                                  int* __restrict__ heads) {
  __shared__ int v[HROWS];
  int t = threadIdx.x;
  int cnt = *counter;
  if (cnt > HROWS) cnt = HROWS;
  v[t] = (t < cnt) ? tmp[t] : 0x7fffffff;
  __syncthreads();
  for (int k = 2; k <= HROWS; k <<= 1) {
    for (int j = k >> 1; j > 0; j >>= 1) {
      int ixj = t ^ j;
      if (ixj > t) {
        int a = v[t], b = v[ixj];
        bool up = ((t & k) == 0);
        if ((a > b) == up) { v[t] = b; v[ixj] = a; }
      }
      __syncthreads();
    }
  }
  heads[t] = (v[t] == 0x7fffffff) ? 0 : v[t];
}

// ---- query build (plain row-major bf16) ----
__global__ void build_q_kernel(const float* __restrict__ ent, const float* __restrict__ rel,
                               const int* __restrict__ heads, const int* __restrict__ rel_id,
                               unsigned short* __restrict__ q) {
  int b = blockIdx.x, k = threadIdx.x;
  int h = heads[b];
  const float* r = rel + (size_t)(*rel_id) * (2 * RANK);
  float re_h = ent[(size_t)h * DIM + k];
  float im_h = ent[(size_t)h * DIM + RANK + k];
  float re_r = r[k], im_r = r[RANK + k];
  q[(size_t)b * DIM + k]        = f2bf(re_h * re_r - im_h * im_r);
  q[(size_t)b * DIM + RANK + k] = f2bf(re_h * im_r + im_h * re_r);
}

// ---- GEMM: out = exp(q(256x512) @ ent^T); per-block partial rowsums ----
// 1563 blocks x 256 thr (4 waves). Tile: 256 rows x 64 cols, BK=32, dbuf LDS B.
// MODE 0: partial[bid*256+row] plain stores. MODE 1: atomicAdd fallback.
template <int MODE>
__global__ __launch_bounds__(256) void gemm_scores_kernel(
    const float* __restrict__ ent, const unsigned short* __restrict__ q,
    float* __restrict__ out, float* __restrict__ partial) {
  __shared__ __align__(16) unsigned short Bs[2][64 * BSTRIDE];  // 2 x 5KB

  const int t = threadIdx.x;
  const int lane = t & 63;
  const int w = t >> 6;
  const int l15 = lane & 15;
  const int lk = lane >> 4;        // 0..3
  const int lk8 = lk * 8;

  const int e0 = blockIdx.x * 64;

  // B staging geometry: 64 cols x 32 k f32; thread n -> col=n>>2, ks=(n&3)*8
  const int scol = t >> 2;
  const int sks = (t & 3) * 8;
  int ge = e0 + scol; if (ge > N_ENT - 1) ge = N_ENT - 1;
  const float* bp = ent + (size_t)ge * DIM + sks;
  unsigned short* bdst0 = &Bs[0][scol * BSTRIDE + sks];
  unsigned short* bdst1 = &Bs[1][scol * BSTRIDE + sks];

  // A fragment pointers: wave w rows [64w, 64w+64)
  const unsigned short* ap[4];
#pragma unroll
  for (int fr = 0; fr < 4; ++fr)
    ap[fr] = q + (size_t)(w * 64 + fr * 16 + l15) * DIM + lk8;

  auto cvt_write = [&](float4 v0, float4 v1, unsigned short* dst) {
    unsigned int r0, r1, r2, r3;
    asm("v_cvt_pk_bf16_f32 %0, %1, %2" : "=v"(r0) : "v"(v0.x), "v"(v0.y));
    asm("v_cvt_pk_bf16_f32 %0, %1, %2" : "=v"(r1) : "v"(v0.z), "v"(v0.w));
    asm("v_cvt_pk_bf16_f32 %0, %1, %2" : "=v"(r2) : "v"(v1.x), "v"(v1.y));
    asm("v_cvt_pk_bf16_f32 %0, %1, %2" : "=v"(r3) : "v"(v1.z), "v"(v1.w));
    u32x4 pk = {r0, r1, r2, r3};
    *reinterpret_cast<u32x4*>(dst) = pk;
  };

  // prologue: B tile 0 + A frags 0
  float4 cb0 = *reinterpret_cast<const float4*>(bp);
  float4 cb1 = *reinterpret_cast<const float4*>(bp + 4);
  short8_t ac[4];
#pragma unroll
  for (int fr = 0; fr < 4; ++fr) ac[fr] = *reinterpret_cast<const short8_t*>(ap[fr]);
  cvt_write(cb0, cb1, bdst0);
  __syncthreads();

  f32x4 acc[4][4] = {};

  for (int kf = 0; kf < 16; ++kf) {
    const int cur = kf & 1;
    float4 nb0, nb1;
    short8_t an[4];
    if (kf < 15) {  // prefetch next tiles (in flight across the MFMAs)
      nb0 = *reinterpret_cast<const float4*>(bp + (kf + 1) * 32);
      nb1 = *reinterpret_cast<const float4*>(bp + (kf + 1) * 32 + 4);
#pragma unroll
      for (int fr = 0; fr < 4; ++fr)
        an[fr] = *reinterpret_cast<const short8_t*>(ap[fr] + (kf + 1) * 32);
    }
    short8_t b[4];
#pragma unroll
    for (int fb = 0; fb < 4; ++fb)
      b[fb] = *reinterpret_cast<const short8_t*>(&Bs[cur][(fb * 16 + l15) * BSTRIDE + lk8]);
#pragma unroll
    for (int fr = 0; fr < 4; ++fr)
#pragma unroll
      for (int fb = 0; fb < 4; ++fb)
        acc[fr][fb] = __builtin_amdgcn_mfma_f32_16x16x32_bf16(ac[fr], b[fb], acc[fr][fb], 0, 0, 0);
    if (kf < 15) {
      cvt_write(nb0, nb1, cur ? bdst0 : bdst1);  // waits vmcnt on nb after MFMAs
#pragma unroll
      for (int fr = 0; fr < 4; ++fr) ac[fr] = an[fr];
    }
    __syncthreads();
  }

  // epilogue: C/D map col=lane&15, row=(lane>>4)*4+reg; store exp(s)
#pragma unroll
  for (int fr = 0; fr < 4; ++fr) {
#pragma unroll
    for (int j = 0; j < 4; ++j) {
      const int row = w * 64 + fr * 16 + lk * 4 + j;
      float psum = 0.0f;
#pragma unroll
      for (int fb = 0; fb < 4; ++fb) {
        const int col = e0 + fb * 16 + l15;
        if (col < N_ENT) {
          float p = __expf(acc[fr][fb][j]);  // |s| small: no max-subtraction
          out[(size_t)row * N_ENT + col] = p;
          psum += p;
        }
      }
      psum += __shfl_xor(psum, 1);
      psum += __shfl_xor(psum, 2);
      psum += __shfl_xor(psum, 4);
      psum += __shfl_xor(psum, 8);
      if (l15 == 0) {
        if (MODE == 0) partial[(size_t)blockIdx.x * HROWS + row] = psum;  // no atomics
        else atomicAdd(&partial[row], psum);
      }
    }
  }
}

// ---- rowsum = sum over blocks of partial ----
__global__ void rowsum_reduce_kernel(const float* __restrict__ partial,
                                     float* __restrict__ rowsum) {
  __shared__ float red[256];
  const int row = blockIdx.x, t = threadIdx.x;
  float s = 0.0f;
  for (int k = t; k < NBLK; k += 256) s += partial[(size_t)k * HROWS + row];
  red[t] = s;
  __syncthreads();
  for (int m = 128; m > 0; m >>= 1) {
    if (t < m) red[t] += red[t + m];
    __syncthreads();
  }
  if (t == 0) rowsum[row] = red[0];
}

// ---- scaling: factor[i] = scaling_i / rowsum_i (out holds exp(s)) ----
__global__ void scaling_kernel(const float* __restrict__ pun, const float* __restrict__ rowsum,
                               const int* __restrict__ obs_idx, const void* __restrict__ mask,
                               const int* __restrict__ flags, float* __restrict__ factor) {
  int i = threadIdx.x;
  int mode = mask_mode(flags);
  float rs = rowsum[i];
  float sume = 0.0f;
  int cnt = 0;
  for (int j = 0; j < 32; ++j) {
    if (mask_at(mask, i * 32 + j, mode)) {
      int tg = obs_idx[i * 32 + j];
      sume += pun[(size_t)i * N_ENT + tg];
      ++cnt;
    }
  }
  float scaling = 1.0f;
  if (cnt > 0) {
    float denom = fmaxf(sume / rs, 1e-30f);
    scaling = (float)cnt / denom;
  }
  factor[i] = scaling / rs;
}

// ---- finalize: out = clamp(threshold(p_un * factor)) in place ----
__global__ __launch_bounds__(256) void finalize_kernel(float* __restrict__ out,
                                                       const float* __restrict__ factor,
                                                       const int* __restrict__ train) {
  int row = blockIdx.y;
  int i4 = blockIdx.x * blockDim.x + threadIdx.x;
  if (i4 >= N_ENT / 4) return;
  float f = factor[row];
  float hi = (*train) ? (1.0f - 0.001f) : 1.0f;
  float4* p = reinterpret_cast<float4*>(out + (size_t)row * N_ENT) + i4;
  float4 v = *p;
  float vals[4] = {v.x, v.y, v.z, v.w};
#pragma unroll
  for (int j = 0; j < 4; ++j) {
    float s = vals[j] * f;
    s = (s > 1e-4f) ? s : 0.0f;
    vals[j] = fminf(s, hi);
  }
  v.x = vals[0]; v.y = vals[1]; v.z = vals[2]; v.w = vals[3];
  *p = v;
}

// ---- observed positions -> 1.0 (train only) ----
__global__ void scatter_obs_kernel(float* __restrict__ out, const int* __restrict__ obs_idx,
                                   const void* __restrict__ mask, const int* __restrict__ flags,
                                   const int* __restrict__ train) {
  if (!(*train)) return;
  int t = blockIdx.x * blockDim.x + threadIdx.x;
  if (t >= HROWS * MAXOBS) return;
  int mode = mask_mode(flags);
  if (mask_at(mask, t, mode))
    out[(size_t)(t >> 5) * N_ENT + obs_idx[t]] = 1.0f;
}

extern "C" void kernel_launch(void* const* d_in, const int* in_sizes, int n_in,
                              void* d_out, int out_size, void* d_ws, size_t ws_size,
                              hipStream_t stream) {
  const float* ent      = (const float*)d_in[0];
  const float* rel      = (const float*)d_in[1];
  const float* head_vec = (const float*)d_in[2];
  const int* obs_idx    = (const int*)d_in[3];
  const void* obs_mask  = d_in[4];
  const int* rel_id     = (const int*)d_in[5];
  const int* train      = (const int*)d_in[7];
  float* out = (float*)d_out;

  char* ws = (char*)d_ws;
  int*   counter = (int*)(ws + 0);
  int*   flags   = (int*)(ws + 4);
  float* rowsum  = (float*)(ws + 64);
  float* factor  = (float*)(ws + 1088);
  int*   tmp     = (int*)(ws + 2112);
  int*   heads   = (int*)(ws + 3136);
  unsigned short* q = (unsigned short*)(ws + 4224);        // 256x512 bf16 = 256KB
  float* partial = (float*)(ws + 4224 + HROWS * DIM * 2);  // [1563][256] f32 = 1.6MB
  const size_t needed = 4224 + (size_t)HROWS * DIM * 2 + (size_t)NBLK * HROWS * 4;
  const bool big_ws = ws_size >= needed;

  hipMemsetAsync(ws, 0, 2112, stream);  // counter + flags + rowsum

  detect_mask_kernel<<<1, 256, 0, stream>>>((const unsigned char*)obs_mask, flags);
  find_heads_kernel<<<(N_ENT + 255) / 256, 256, 0, stream>>>(head_vec, counter, tmp);
  sort_heads_kernel<<<1, 256, 0, stream>>>(counter, tmp, heads);
  build_q_kernel<<<HROWS, 256, 0, stream>>>(ent, rel, heads, rel_id, q);
  if (big_ws) {
    gemm_scores_kernel<0><<<NBLK, 256, 0, stream>>>(ent, q, out, partial);
    rowsum_reduce_kernel<<<HROWS, 256, 0, stream>>>(partial, rowsum);
  } else {
    gemm_scores_kernel<1><<<NBLK, 256, 0, stream>>>(ent, q, out, rowsum);
  }
  scaling_kernel<<<1, 256, 0, stream>>>(out, rowsum, obs_idx, obs_mask, flags, factor);
  finalize_kernel<<<dim3((N_ENT / 4 + 255) / 256, HROWS), 256, 0, stream>>>(out, factor, train);
  scatter_obs_kernel<<<(HROWS * MAXOBS + 255) / 256, 256, 0, stream>>>(out, obs_idx, obs_mask, flags, train);
}